// Round 13
// baseline (222.182 us; speedup 1.0000x reference)
//
#include <hip/hip_runtime.h>

// FFLayer: out = relu( (x / (||x||_2 + 1e-4)) @ W^T + b )
// x: [131072,1024] f32, W: [256,1024] f32, b: [256] f32, out: [131072,256] f32
//
// Round 13: HBM-pattern probe. A fetched in 1KB-contiguous row-chunks
// (one gload_lds wave-op = one row's 1KB), vs 256B chunks in r5-r12.
// BM=64, 512 thr, 8 waves (2Mx4N, 32x64 tiles). A 2 x 64KB (group = 8
// steps), B 2 x 16KB staged 1-ahead (L2-resident). LDS = 160KB exactly.
// FIFO-simmed waits: r==0 -> vmcnt(3), r in 1..5 -> vmcnt(1), else 0.

#define IN_F   1024
#define OUT_F  256
#define BATCH  131072
#define BM     64
#define NKT    32      // BK=32 compute steps
#define EPSV   1e-4f

typedef __attribute__((ext_vector_type(8))) __bf16 bf16x8;
typedef __attribute__((ext_vector_type(4))) __bf16 bf16x4;
typedef __attribute__((ext_vector_type(4))) float  f32x4;

__device__ __forceinline__ void gload_lds16(const void* g, void* lds) {
  __builtin_amdgcn_global_load_lds(
      (const __attribute__((address_space(1))) void*)g,
      (__attribute__((address_space(3))) void*)lds, 16, 0, 0);
}

#define VM_WAIT(N) do { asm volatile("s_waitcnt vmcnt(" #N ")" ::: "memory"); \
                        __builtin_amdgcn_sched_barrier(0); } while (0)

// W (f32 [256][1024]) -> bf16 [256][1024] in d_ws (512 KB)
__global__ void wconv_kernel(const float* __restrict__ W, __bf16* __restrict__ Wb) {
  const int t = blockIdx.x * blockDim.x + threadIdx.x;
  const float4 v = reinterpret_cast<const float4*>(W)[t];
  bf16x4 h;
  h[0] = (__bf16)v.x; h[1] = (__bf16)v.y; h[2] = (__bf16)v.z; h[3] = (__bf16)v.w;
  reinterpret_cast<bf16x4*>(Wb)[t] = h;
}

__global__ __launch_bounds__(512, 2)
void ffl_kernel(const float* __restrict__ x, const __bf16* __restrict__ Wb,
                const float* __restrict__ bias, float* __restrict__ out) {
  // LDS: A 2 x 64KB at 0/65536 (f32 [64 rows][1KB], granule-XOR by row&7)
  //      B 2 x 16KB at 131072/147456 (bf16 [256 rows][64B], r12 layout)
  //      norms: 256B at 131072 (B area, written post-loop)
  //      epilogue stg [64][260] f32 = 66560B reuses A area
  __shared__ __align__(16) char smem[163840];
  char* const Ab[2] = {smem, smem + 65536};
  char* const Bb[2] = {smem + 131072, smem + 147456};

  const int tid  = threadIdx.x;
  const int lane = tid & 63;
  const int wave = tid >> 6;     // 8 waves: 2(M) x 4(N), wave tile 32x64
  const int wr   = wave >> 2;
  const int wc   = wave & 3;
  const int rm   = lane & 15;
  const int q    = lane >> 4;
  const size_t block_row = (size_t)blockIdx.x * BM;
  const int phg = blockIdx.x & 3;             // K-rotation (4 A-groups)

  // ---- B staging: 2 insts/step. Chunk c=2w+i (1KB = 16 rows x 64B).
  const __bf16* bSrc[2]; int bDst[2];
  #pragma unroll
  for (int i = 0; i < 2; ++i) {
    const int c    = 2 * wave + i;
    const int brow = 16 * c + (lane >> 2);
    const int bs   = (lane & 3) ^ ((brow >> 1) & 3);
    bSrc[i] = Wb + (size_t)brow * IN_F + bs * 8;
    bDst[i] = c * 1024;
  }

  f32x4 acc[2][4];
  #pragma unroll
  for (int m = 0; m < 2; ++m)
    #pragma unroll
    for (int n = 0; n < 4; ++n)
      acc[m][n] = (f32x4){0.f, 0.f, 0.f, 0.f};

  float ssq0 = 0.f, ssq1 = 0.f;

  // ---- A staging: one inst = one row's 1KB contiguous (64 lanes x 16B).
  //      Wave w owns rows 8w..8w+7; inst i -> row 8w+i; src granule lane^i.
  auto stageAinst = [&](int g, int i) {
    const int pg   = (g + phg) & 3;           // physical 1KB window
    const int rloc = 8 * wave + i;
    gload_lds16(x + (block_row + rloc) * IN_F + pg * 256 + ((lane ^ i) << 2),
                Ab[g & 1] + rloc * 1024);
  };
  // ---- B: physical step pk matches A's rotation.
  auto stageB = [&](int s) {
    const int pk = ((((s >> 3) + phg) & 3) << 3) + (s & 7);
    gload_lds16(bSrc[0] + pk * 32, Bb[s & 1] + bDst[0]);
    gload_lds16(bSrc[1] + pk * 32, Bb[s & 1] + bDst[1]);
  };

  // -------- prologue: full A group 0 (8 x 1KB rows/wave) + B0 --------
  #pragma unroll
  for (int i = 0; i < 8; ++i) stageAinst(0, i);
  stageB(0);
  VM_WAIT(0);
  __builtin_amdgcn_s_barrier();

  // -------- main loop: 32 steps of BK=32 --------
  #pragma unroll
  for (int kt = 0; kt < NKT; ++kt) {
    const int r  = kt & 7;
    const int gn = (kt >> 3) + 1;             // group being prefetched

    if (kt + 1 < NKT) stageB(kt + 1);         // 2 insts (1-ahead, L2)
    if (gn < 4) {                             // A(gn): 3+1+1+1+1+1 over r=0..5
      if (r == 0) { stageAinst(gn, 0); stageAinst(gn, 1); stageAinst(gn, 2); }
      else if (r <= 5) { stageAinst(gn, r + 2); }
    }

    const char* abuf = Ab[(kt >> 3) & 1];
    const char* bbuf = Bb[kt & 1];
    const int   w8   = (kt & 7) * 8;          // granule window within 1KB row

    // A fragments (f32 -> bf16) + exact sumsq
    bf16x8 aF[2];
    #pragma unroll
    for (int m = 0; m < 2; ++m) {
      const int ra = wr * 32 + m * 16 + rm;
      const char* ab = abuf + ra * 1024;
      const int sw = ra & 7;
      const int g0 = w8 + 2 * q;
      const f32x4 lo = *reinterpret_cast<const f32x4*>(ab + ((g0)     ^ sw) * 16);
      const f32x4 hi = *reinterpret_cast<const f32x4*>(ab + ((g0 + 1) ^ sw) * 16);
      float& ssq = m ? ssq1 : ssq0;
      ssq += lo[0]*lo[0] + lo[1]*lo[1] + lo[2]*lo[2] + lo[3]*lo[3]
           + hi[0]*hi[0] + hi[1]*hi[1] + hi[2]*hi[2] + hi[3]*hi[3];
      bf16x8 a;
      a[0]=(__bf16)lo[0]; a[1]=(__bf16)lo[1]; a[2]=(__bf16)lo[2]; a[3]=(__bf16)lo[3];
      a[4]=(__bf16)hi[0]; a[5]=(__bf16)hi[1]; a[6]=(__bf16)hi[2]; a[7]=(__bf16)hi[3];
      aF[m] = a;
    }

    #pragma unroll
    for (int n = 0; n < 4; ++n) {
      const int rb = wc * 64 + n * 16 + rm;
      const bf16x8 bF = *reinterpret_cast<const bf16x8*>(
          bbuf + rb * 64 + (q ^ ((rb >> 1) & 3)) * 16);
      acc[0][n] = __builtin_amdgcn_mfma_f32_16x16x32_bf16(aF[0], bF, acc[0][n], 0, 0, 0);
      acc[1][n] = __builtin_amdgcn_mfma_f32_16x16x32_bf16(aF[1], bF, acc[1][n], 0, 0, 0);
    }

    // FIFO-simmed waits: retire exactly what step kt+1 needs.
    if (gn < 4 && r == 0)            { VM_WAIT(3); }
    else if (gn < 4 && r >= 1 && r <= 5) { VM_WAIT(1); }
    else                             { VM_WAIT(0); }
    __builtin_amdgcn_s_barrier();
  }

  // -------- row L2-norms --------
  ssq0 += __shfl_xor(ssq0, 16); ssq0 += __shfl_xor(ssq0, 32);
  ssq1 += __shfl_xor(ssq1, 16); ssq1 += __shfl_xor(ssq1, 32);
  float* norms = reinterpret_cast<float*>(smem + 131072);   // B area, dead now
  if (wc == 0 && q == 0) {
    norms[wr * 32 + rm]      = 1.0f / (sqrtf(ssq0) + EPSV);
    norms[wr * 32 + 16 + rm] = 1.0f / (sqrtf(ssq1) + EPSV);
  }
  __syncthreads();

  // -------- scale + bias + relu -> LDS transpose (A area, dead now) --------
  float* stg = reinterpret_cast<float*>(smem);   // [64][260] f32 = 66560B
  const int col0 = wc * 64 + rm;
  #pragma unroll
  for (int n = 0; n < 4; ++n) {
    const float bn = bias[col0 + n * 16];
    #pragma unroll
    for (int m = 0; m < 2; ++m) {
      #pragma unroll
      for (int j = 0; j < 4; ++j) {
        const int lr = wr * 32 + m * 16 + q * 4 + j;
        stg[lr * 260 + col0 + n * 16] = fmaxf(acc[m][n][j] * norms[lr] + bn, 0.f);
      }
    }
  }
  __syncthreads();

  // -------- coalesced store: 64 rows, 8 threads/row, full 128B lines ------
  const int rr = tid >> 3, p = tid & 7;
  const float* srow = stg + rr * 260;
  float* orow = out + (block_row + rr) * OUT_F;
  #pragma unroll
  for (int i = 0; i < 8; ++i) {
    const int f = i * 8 + p;
    const f32x4 v = *reinterpret_cast<const f32x4*>(srow + f * 4);
    *reinterpret_cast<f32x4*>(orow + f * 4) = v;
  }
}

extern "C" void kernel_launch(void* const* d_in, const int* in_sizes, int n_in,
                              void* d_out, int out_size, void* d_ws, size_t ws_size,
                              hipStream_t stream) {
  const float* x = (const float*)d_in[0];
  const float* W = (const float*)d_in[1];
  const float* b = (const float*)d_in[2];
  float* out = (float*)d_out;
  __bf16* Wb = (__bf16*)d_ws;   // 512 KB scratch

  wconv_kernel<<<(OUT_F * IN_F / 4) / 256, 256, 0, stream>>>(W, Wb);
  ffl_kernel<<<BATCH / BM, 512, 0, stream>>>(x, Wb, b, out);
}

// Round 15
// 186.437 us; speedup vs baseline: 1.1917x; 1.1917x over previous
//
#include <hip/hip_runtime.h>

// FFLayer: out = relu( (x / (||x||_2 + 1e-4)) @ W^T + b )
// x: [131072,1024] f32, W: [256,1024] f32, b: [256] f32, out: [131072,256] f32
//
// Round 15 = round 14's K-loop (2 blocks/CU, BM=128, 512 thr, 8 waves of
// 64x64, A 3x16KB + B 2x16KB, steady vmcnt(2)) with the epilogue FIXED:
//  - norms at offset 67584 (outside stg [0,67584), inside dead B area)
//  - two-pass transpose store, full 128-col coverage (8 f32x4/thread)

#define IN_F   1024
#define OUT_F  256
#define BATCH  131072
#define BM     128
#define NKT    32      // BK=32 compute steps
#define EPSV   1e-4f

typedef __attribute__((ext_vector_type(8))) __bf16 bf16x8;
typedef __attribute__((ext_vector_type(4))) __bf16 bf16x4;
typedef __attribute__((ext_vector_type(4))) float  f32x4;

__device__ __forceinline__ void gload_lds16(const void* g, void* lds) {
  __builtin_amdgcn_global_load_lds(
      (const __attribute__((address_space(1))) void*)g,
      (__attribute__((address_space(3))) void*)lds, 16, 0, 0);
}

#define VM_WAIT(N) do { asm volatile("s_waitcnt vmcnt(" #N ")" ::: "memory"); \
                        __builtin_amdgcn_sched_barrier(0); } while (0)

// W (f32 [256][1024]) -> bf16 [256][1024] in d_ws (512 KB)
__global__ void wconv_kernel(const float* __restrict__ W, __bf16* __restrict__ Wb) {
  const int t = blockIdx.x * blockDim.x + threadIdx.x;
  const float4 v = reinterpret_cast<const float4*>(W)[t];
  bf16x4 h;
  h[0] = (__bf16)v.x; h[1] = (__bf16)v.y; h[2] = (__bf16)v.z; h[3] = (__bf16)v.w;
  reinterpret_cast<bf16x4*>(Wb)[t] = h;
}

__global__ __launch_bounds__(512, 2)
void ffl_kernel(const float* __restrict__ x, const __bf16* __restrict__ Wb,
                const float* __restrict__ bias, float* __restrict__ out) {
  // LDS (80KB exactly -> 2 blocks/CU):
  //   A: 3 x 16KB at 0/16384/32768   f32 [128 rows][128B], src-XOR-swizzled
  //   B: 2 x 16KB at 49152/65536     bf16 [256 rows][64B], r8 layout
  //   epilogue stg [128][132] f32 = 67584B reuses [0, 67584)
  //   norms: 512B at 67584 (inside dead B[1] area, AFTER stg)
  __shared__ __align__(16) char smem[81920];
  char* const Ab[3] = {smem, smem + 16384, smem + 32768};
  char* const Bb[2] = {smem + 49152, smem + 65536};

  const int tid  = threadIdx.x;
  const int lane = tid & 63;
  const int wave = tid >> 6;     // 8 waves: 2(M) x 4(N), wave tile 64x64
  const int wr   = wave >> 2;    // 0..1, rows wr*64..+63
  const int wc   = wave & 3;     // 0..3, cols wc*64..+63
  const int rm   = lane & 15;
  const int q    = lane >> 4;
  const size_t block_row = (size_t)blockIdx.x * BM;
  const int phg = blockIdx.x & 31;            // K-rotation (BK=32 steps)

  // ---- A staging: 2 insts/thread/step. Chunk c=2w+i (1KB = 8 rows x 128B).
  const float* aSrc[2]; int aDst[2];
  #pragma unroll
  for (int i = 0; i < 2; ++i) {
    const int c  = 2 * wave + i;
    const int rl = lane >> 3;                  // row within chunk (== row&7)
    const int s  = (lane & 7) ^ rl;            // pre-swizzled source granule
    aSrc[i] = x + (block_row + 8 * c + rl) * IN_F + s * 4;
    aDst[i] = c * 1024;
  }
  // ---- B staging: 2 insts/thread/step. Chunk c=2w+i (1KB = 16 rows x 64B).
  const __bf16* bSrc[2]; int bDst[2];
  #pragma unroll
  for (int i = 0; i < 2; ++i) {
    const int c    = 2 * wave + i;
    const int brow = 16 * c + (lane >> 2);
    const int bs   = (lane & 3) ^ ((brow >> 1) & 3);
    bSrc[i] = Wb + (size_t)brow * IN_F + bs * 8;
    bDst[i] = c * 1024;
  }

  f32x4 acc[4][4];
  #pragma unroll
  for (int m = 0; m < 4; ++m)
    #pragma unroll
    for (int n = 0; n < 4; ++n)
      acc[m][n] = (f32x4){0.f, 0.f, 0.f, 0.f};

  float ssq[4] = {0.f, 0.f, 0.f, 0.f};

  auto stageA = [&](int s) {      // logical step -> physical (s+phg)&31
    const int pk = (s + phg) & 31;
    gload_lds16(aSrc[0] + pk * 32, Ab[s % 3] + aDst[0]);
    gload_lds16(aSrc[1] + pk * 32, Ab[s % 3] + aDst[1]);
  };
  auto stageB = [&](int s) {
    const int pk = (s + phg) & 31;
    gload_lds16(bSrc[0] + pk * 32, Bb[s & 1] + bDst[0]);
    gload_lds16(bSrc[1] + pk * 32, Bb[s & 1] + bDst[1]);
  };

  // -------- prologue: A0(2) B0(2) A1(2) --------
  stageA(0);
  stageB(0);
  stageA(1);
  VM_WAIT(2);                    // retire A0,B0; flight = A1(2)
  __builtin_amdgcn_s_barrier();

  // -------- main loop: 32 steps of BK=32 (FIFO sim-verified) --------
  #pragma unroll
  for (int kt = 0; kt < NKT; ++kt) {
    if (kt + 1 < NKT) stageB(kt + 1);          // 2 insts
    if (kt + 2 < NKT) stageA(kt + 2);          // 2 insts

    const char* abuf = Ab[kt % 3];
    const char* bbuf = Bb[kt & 1];

    // A fragments (f32 -> bf16) + exact sumsq: 4 m-frags, rows wr*64+m*16+rm
    bf16x8 aF[4];
    #pragma unroll
    for (int m = 0; m < 4; ++m) {
      const int ra = wr * 64 + m * 16 + rm;
      const char* ab = abuf + ra * 128;
      const int sw = ra & 7;
      const f32x4 lo = *reinterpret_cast<const f32x4*>(ab + ((2 * q)     ^ sw) * 16);
      const f32x4 hi = *reinterpret_cast<const f32x4*>(ab + ((2 * q + 1) ^ sw) * 16);
      ssq[m] += lo[0]*lo[0] + lo[1]*lo[1] + lo[2]*lo[2] + lo[3]*lo[3]
              + hi[0]*hi[0] + hi[1]*hi[1] + hi[2]*hi[2] + hi[3]*hi[3];
      bf16x8 a;
      a[0]=(__bf16)lo[0]; a[1]=(__bf16)lo[1]; a[2]=(__bf16)lo[2]; a[3]=(__bf16)lo[3];
      a[4]=(__bf16)hi[0]; a[5]=(__bf16)hi[1]; a[6]=(__bf16)hi[2]; a[7]=(__bf16)hi[3];
      aF[m] = a;
    }

    #pragma unroll
    for (int n = 0; n < 4; ++n) {
      const int rb = wc * 64 + n * 16 + rm;
      const bf16x8 bF = *reinterpret_cast<const bf16x8*>(
          bbuf + rb * 64 + (q ^ ((rb >> 1) & 3)) * 16);
      #pragma unroll
      for (int m = 0; m < 4; ++m)
        acc[m][n] = __builtin_amdgcn_mfma_f32_16x16x32_bf16(aF[m], bF, acc[m][n], 0, 0, 0);
    }

    // steady vmcnt(2): retires A(kt+1)+B(kt+1), keeps A(kt+2) in flight
    if (kt < 30) { VM_WAIT(2); } else { VM_WAIT(0); }
    __builtin_amdgcn_s_barrier();
  }

  // -------- row L2-norms: reduce over the 4 q-groups --------
  #pragma unroll
  for (int m = 0; m < 4; ++m) {
    ssq[m] += __shfl_xor(ssq[m], 16);
    ssq[m] += __shfl_xor(ssq[m], 32);
  }
  float* norms = reinterpret_cast<float*>(smem + 67584);   // outside stg
  if (wc == 0 && q == 0) {
    #pragma unroll
    for (int m = 0; m < 4; ++m)
      norms[wr * 64 + m * 16 + rm] = 1.0f / (sqrtf(ssq[m]) + EPSV);
  }
  __syncthreads();

  // -------- epilogue: two col-half passes through stg [128][132] f32 ------
  float* stg = reinterpret_cast<float*>(smem);
  const int col0 = wc * 64 + rm;               // this wave's output col base
  const int r = tid >> 2, p = tid & 3;         // store coords: 4 thr/row
  #pragma unroll
  for (int half = 0; half < 2; ++half) {
    if ((wc >> 1) == half) {
      // waves wc=2h (stg cols 0..63) and wc=2h+1 (stg cols 64..127)
      #pragma unroll
      for (int n = 0; n < 4; ++n) {
        const float bn = bias[col0 + n * 16];
        #pragma unroll
        for (int m = 0; m < 4; ++m) {
          #pragma unroll
          for (int j = 0; j < 4; ++j) {
            const int lr = wr * 64 + m * 16 + q * 4 + j;
            stg[lr * 132 + (wc & 1) * 64 + n * 16 + rm] =
                fmaxf(acc[m][n][j] * norms[lr] + bn, 0.f);
          }
        }
      }
    }
    __syncthreads();
    // store this half: 128 rows x 128 cols = 4 thr/row x 8 f32x4
    float* orow = out + (block_row + r) * OUT_F + half * 128;
    const float* srow = stg + r * 132;
    #pragma unroll
    for (int i = 0; i < 8; ++i) {
      const int f = i * 4 + p;                 // f32x4 index 0..31
      const f32x4 v = *reinterpret_cast<const f32x4*>(srow + f * 4);
      *reinterpret_cast<f32x4*>(orow + f * 4) = v;
    }
    __syncthreads();
  }
}

extern "C" void kernel_launch(void* const* d_in, const int* in_sizes, int n_in,
                              void* d_out, int out_size, void* d_ws, size_t ws_size,
                              hipStream_t stream) {
  const float* x = (const float*)d_in[0];
  const float* W = (const float*)d_in[1];
  const float* b = (const float*)d_in[2];
  float* out = (float*)d_out;
  __bf16* Wb = (__bf16*)d_ws;   // 512 KB scratch

  wconv_kernel<<<(OUT_F * IN_F / 4) / 256, 256, 0, stream>>>(W, Wb);
  ffl_kernel<<<BATCH / BM, 512, 0, stream>>>(x, Wb, b, out);
}

// Round 16
// 171.571 us; speedup vs baseline: 1.2950x; 1.0866x over previous
//
#include <hip/hip_runtime.h>

// FFLayer: out = relu( (x / (||x||_2 + 1e-4)) @ W^T + b )
// x: [131072,1024] f32, W: [256,1024] f32, b: [256] f32, out: [131072,256] f32
//
// Round 16 = round 8 (best, 170.6us) VERBATIM (BM=128, 1024 thr, 16 waves of
// 32x64, A f32 3x32KB BK=64-groups, B bf16 4x16KB, K-rotation, FIFO waits
// 6/4 steady) + three micro-levers:
//  (1) all frag ds_reads hoisted to the top of the step (LDS port starts at
//      barrier-exit, not after the VMEM issue burst),
//  (2) bF[4] pre-read -> pure 8-MFMA cluster,
//  (3) s_setprio(1) around the MFMA cluster (T5: compute waves vs DMA waves).

#define IN_F   1024
#define OUT_F  256
#define BATCH  131072
#define BM     128
#define NKT    32      // BK=32 compute steps
#define EPSV   1e-4f

typedef __attribute__((ext_vector_type(8))) __bf16 bf16x8;
typedef __attribute__((ext_vector_type(4))) __bf16 bf16x4;
typedef __attribute__((ext_vector_type(4))) float  f32x4;

__device__ __forceinline__ void gload_lds16(const void* g, void* lds) {
  __builtin_amdgcn_global_load_lds(
      (const __attribute__((address_space(1))) void*)g,
      (__attribute__((address_space(3))) void*)lds, 16, 0, 0);
}

#define VM_WAIT(N) do { asm volatile("s_waitcnt vmcnt(" #N ")" ::: "memory"); \
                        __builtin_amdgcn_sched_barrier(0); } while (0)

// W (f32 [256][1024]) -> bf16 [256][1024] in d_ws (512 KB)
__global__ void wconv_kernel(const float* __restrict__ W, __bf16* __restrict__ Wb) {
  const int t = blockIdx.x * blockDim.x + threadIdx.x;
  const float4 v = reinterpret_cast<const float4*>(W)[t];
  bf16x4 h;
  h[0] = (__bf16)v.x; h[1] = (__bf16)v.y; h[2] = (__bf16)v.z; h[3] = (__bf16)v.w;
  reinterpret_cast<bf16x4*>(Wb)[t] = h;
}

__global__ __launch_bounds__(1024, 4)
void ffl_kernel(const float* __restrict__ x, const __bf16* __restrict__ Wb,
                const float* __restrict__ bias, float* __restrict__ out) {
  // A bufs: 3 x 32KB at 0/32768/65536 (f32, [128 rows][256B], granule-swizzled)
  // B bufs: 4 x 16KB at 98304..163840 (bf16, [256 rows][64B], swizzled)
  // norms: 512B at 163328 (inside B[3], dead after the K-loop)
  // Epilogue stg [128][260] f32 = 133120B reuses [0,133120).
  __shared__ __align__(16) char smem[163840];
  char* const Ab[3] = {smem, smem + 32768, smem + 65536};
  char* const Bb[4] = {smem + 98304, smem + 114688, smem + 131072, smem + 147456};

  const int tid  = threadIdx.x;
  const int lane = tid & 63;
  const int wave = tid >> 6;     // 16 waves: 4(M) x 4(N)
  const int wr   = wave >> 2;
  const int wc   = wave & 3;
  const int rm   = lane & 15;
  const int q    = lane >> 4;
  const size_t block_row = (size_t)blockIdx.x * BM;
  const int phg = blockIdx.x & 15;            // K-rotation phase (A-groups)

  // ---- A staging: 2 issues/thread/group. Chunk c=2w+i (1KB = 4 rows x 256B).
  const float* aSrc[2]; int aDst[2];
  #pragma unroll
  for (int i = 0; i < 2; ++i) {
    const int c   = 2 * wave + i;
    const int row = 4 * c + (lane >> 4);
    const int s   = (lane & 15) ^ (row & 7);
    aSrc[i] = x + (block_row + row) * IN_F + s * 4;
    aDst[i] = c * 1024;
  }
  // ---- B staging: 1 issue/thread/step. Chunk = wave (1KB = 16 rows x 64B).
  const int brow = 16 * wave + (lane >> 2);
  const int bs   = (lane & 3) ^ ((brow >> 1) & 3);
  const __bf16* bSrc = Wb + (size_t)brow * IN_F + bs * 8;
  const int bDst = wave * 1024;

  f32x4 acc[2][4];
  #pragma unroll
  for (int m = 0; m < 2; ++m)
    #pragma unroll
    for (int n = 0; n < 4; ++n)
      acc[m][n] = (f32x4){0.f, 0.f, 0.f, 0.f};

  float ssq0 = 0.f, ssq1 = 0.f;

  auto stageA = [&](int g) {      // logical group g -> physical (g+phg)&15
    const int pg = (g + phg) & 15;
    gload_lds16(aSrc[0] + pg * 64, Ab[g % 3] + aDst[0]);
    gload_lds16(aSrc[1] + pg * 64, Ab[g % 3] + aDst[1]);
  };
  auto stageB = [&](int kt) {     // logical step -> physical (kt+2*phg)&31
    const int pk = (kt + 2 * phg) & 31;
    gload_lds16(bSrc + pk * 32, Bb[kt & 3] + bDst);
  };

  // -------- prologue: A(g0) A(g1) B0 B1 B2 in flight --------
  stageA(0);
  stageA(1);
  stageB(0);
  stageB(1);
  stageB(2);
  VM_WAIT(2);                    // A0,A1,B0 landed; B1,B2 in flight
  __builtin_amdgcn_s_barrier();

  // -------- main loop: 32 steps of BK=32 --------
  #pragma unroll
  for (int kt = 0; kt < NKT; ++kt) {
    const char* abuf = Ab[(kt >> 1) % 3];
    const char* bbuf = Bb[kt & 3];
    const int   gb   = (kt & 1) * 8 + 2 * q;   // A granule base within 256B row

    // (1) frag ds_reads FIRST: LDS port starts draining at barrier-exit.
    f32x4 lo[2], hi[2];
    #pragma unroll
    for (int m = 0; m < 2; ++m) {
      const int ra = wr * 32 + m * 16 + rm;
      const char* ab = abuf + ra * 256;
      const int sw = ra & 7;
      lo[m] = *reinterpret_cast<const f32x4*>(ab + ((gb)     ^ sw) * 16);
      hi[m] = *reinterpret_cast<const f32x4*>(ab + ((gb + 1) ^ sw) * 16);
    }
    bf16x8 bF[4];
    #pragma unroll
    for (int n = 0; n < 4; ++n) {
      const int rb = wc * 64 + n * 16 + rm;
      bF[n] = *reinterpret_cast<const bf16x8*>(
          bbuf + rb * 64 + (q ^ ((rb >> 1) & 3)) * 16);
    }

    // (2) stage issues after the ds_read burst (async pipes, different bufs)
    if (kt + 3 < NKT) stageB(kt + 3);
    if ((kt & 1) == 0 && (kt / 2 + 2) < 16) stageA(kt / 2 + 2);

    // ssq + cvt
    bf16x8 aF[2];
    #pragma unroll
    for (int m = 0; m < 2; ++m) {
      float& ssq = m ? ssq1 : ssq0;
      ssq += lo[m][0]*lo[m][0] + lo[m][1]*lo[m][1] + lo[m][2]*lo[m][2] + lo[m][3]*lo[m][3]
           + hi[m][0]*hi[m][0] + hi[m][1]*hi[m][1] + hi[m][2]*hi[m][2] + hi[m][3]*hi[m][3];
      bf16x8 a;
      a[0]=(__bf16)lo[m][0]; a[1]=(__bf16)lo[m][1]; a[2]=(__bf16)lo[m][2]; a[3]=(__bf16)lo[m][3];
      a[4]=(__bf16)hi[m][0]; a[5]=(__bf16)hi[m][1]; a[6]=(__bf16)hi[m][2]; a[7]=(__bf16)hi[m][3];
      aF[m] = a;
    }

    // (3) pure MFMA cluster under raised priority
    __builtin_amdgcn_s_setprio(1);
    #pragma unroll
    for (int n = 0; n < 4; ++n) {
      acc[0][n] = __builtin_amdgcn_mfma_f32_16x16x32_bf16(aF[0], bF[n], acc[0][n], 0, 0, 0);
      acc[1][n] = __builtin_amdgcn_mfma_f32_16x16x32_bf16(aF[1], bF[n], acc[1][n], 0, 0, 0);
    }
    __builtin_amdgcn_s_setprio(0);

    // FIFO-simulated waits (r8 verbatim): steady even->6, odd->4;
    // startup kt=0 ->4; tail kt=28->4, kt=29->1, kt>=30->0.
    if (kt == 29)                              { VM_WAIT(1); }
    else if (kt >= 30)                         { VM_WAIT(0); }
    else if (kt == 0 || kt == 28 || (kt & 1))  { VM_WAIT(4); }
    else                                       { VM_WAIT(6); }
    __builtin_amdgcn_s_barrier();
  }

  // -------- row L2-norms --------
  ssq0 += __shfl_xor(ssq0, 16); ssq0 += __shfl_xor(ssq0, 32);
  ssq1 += __shfl_xor(ssq1, 16); ssq1 += __shfl_xor(ssq1, 32);
  float* norms = reinterpret_cast<float*>(smem + 163328);
  if (wc == 0 && q == 0) {
    norms[wr * 32 + rm]      = 1.0f / (sqrtf(ssq0) + EPSV);
    norms[wr * 32 + 16 + rm] = 1.0f / (sqrtf(ssq1) + EPSV);
  }
  __syncthreads();

  // -------- scale + bias + relu -> LDS transpose --------
  float* stg = reinterpret_cast<float*>(smem);   // [128][260] f32 = 133120B
  const int col0 = wc * 64 + rm;
  #pragma unroll
  for (int n = 0; n < 4; ++n) {
    const float bn = bias[col0 + n * 16];
    #pragma unroll
    for (int m = 0; m < 2; ++m) {
      #pragma unroll
      for (int j = 0; j < 4; ++j) {
        const int lr = wr * 32 + m * 16 + q * 4 + j;
        stg[lr * 260 + col0 + n * 16] = fmaxf(acc[m][n][j] * norms[lr] + bn, 0.f);
      }
    }
  }
  __syncthreads();

  // -------- coalesced store: full 128B lines --------
  const int r = tid >> 3, p = tid & 7;       // 128 rows, 8 threads/row
  const float* srow = stg + r * 260;
  float* orow = out + (block_row + r) * OUT_F;
  #pragma unroll
  for (int i = 0; i < 8; ++i) {
    const int f = i * 8 + p;
    const f32x4 v = *reinterpret_cast<const f32x4*>(srow + f * 4);
    *reinterpret_cast<f32x4*>(orow + f * 4) = v;
  }
}

extern "C" void kernel_launch(void* const* d_in, const int* in_sizes, int n_in,
                              void* d_out, int out_size, void* d_ws, size_t ws_size,
                              hipStream_t stream) {
  const float* x = (const float*)d_in[0];
  const float* W = (const float*)d_in[1];
  const float* b = (const float*)d_in[2];
  float* out = (float*)d_out;
  __bf16* Wb = (__bf16*)d_ws;   // 512 KB scratch

  wconv_kernel<<<(OUT_F * IN_F / 4) / 256, 256, 0, stream>>>(W, Wb);
  ffl_kernel<<<BATCH / BM, 1024, 0, stream>>>(x, Wb, b, out);
}